// Round 10
// baseline (207.149 us; speedup 1.0000x reference)
//
#include <hip/hip_runtime.h>
#include <hip/hip_bf16.h>

// Shapes (fixed by the reference):
//   edges [E=4096,2] i32 | neigh_idx [N=1e5,K=10] i32 | features [N,256] f32
//   W1 [128,256] | W2 [128,128] | Wc [2,128] f32 -> out [E,2] f32
//
// Restructure: z = features @ W1^T (bf16 MFMA); per-edge 2-hop mean/relu/mean
// on z rows; classifier folded to M2 = Wc@W2.
//
// R10: aggregate gather loop restructured for deep MLP (same lesson as R9's
//      gemm staging): per k-group of 5 k's, batch-issue all 25 uint2 row-pair
//      loads into registers (50 VGPRs, compile-time indices), THEN unpack and
//      accumulate. Previously load->accumulate interleaved per pair let the
//      compiler keep only a shallow load window (R5 pattern: VGPR=52).
//      gemm_z unchanged from R9 (best measured config).

typedef __bf16 bf16x8 __attribute__((ext_vector_type(8)));
typedef float f32x4 __attribute__((ext_vector_type(4)));

#define FEAT 256
#define EMB  128
#define KNB  10
#define BM   64    // gemm M-tile rows; LDS = 64*(256+8)*2B = 33.8 KB

__device__ inline unsigned short f2b(float f) {
  unsigned int u = __float_as_uint(f);
  unsigned int r = (u + 0x7fffu + ((u >> 16) & 1u)) >> 16;  // RNE
  return (unsigned short)r;
}
__device__ inline float b2f(unsigned int s) {
  return __uint_as_float(s << 16);
}

// ---- gemm_z: z = feat @ W1^T (bf16 MFMA, f32 accum, bf16 out) -----------
// 512 threads (8 waves), BM=64 rows/block. Wave w owns cols [16w,16w+16).
// Staging phase 1: 8 batched global float4 loads -> registers (deep MLP).
// Staging phase 2: convert f32->bf16, write padded LDS.
// Last block computes M2 = Wc@W2 instead.

__global__ __launch_bounds__(512, 4) void gemm_z(
    const float* __restrict__ feat, const float* __restrict__ W1,
    const float* __restrict__ W2, const float* __restrict__ Wc,
    unsigned short* __restrict__ z, float* __restrict__ M2, int M) {
  __shared__ unsigned short As[BM][FEAT + 8];   // stride 528B

  if (blockIdx.x == gridDim.x - 1) {
    int t = threadIdx.x;
    if (t < 256) {
      int c = t >> 7, d = t & 127;
      float s = 0.f;
      for (int g = 0; g < EMB; ++g) s += Wc[c * EMB + g] * W2[g * EMB + d];
      M2[t] = s;
    }
    return;
  }

  const int tid  = threadIdx.x;
  const int wid  = tid >> 6;
  const int lane = tid & 63;
  const int m0   = blockIdx.x * BM;

  // B fragments: lane holds col=(lane&15), k = kk*32 + (lane>>4)*8 + i
  const int col = wid * 16 + (lane & 15);
  const int kof = (lane >> 4) * 8;
  bf16x8 bfrag[8];
#pragma unroll
  for (int kk = 0; kk < 8; ++kk) {
    const float* src = &W1[col * FEAT + kk * 32 + kof];
    float4 lo = *reinterpret_cast<const float4*>(src);
    float4 hi = *reinterpret_cast<const float4*>(src + 4);
    union { unsigned short s[8]; bf16x8 v; } cvt;
    cvt.s[0] = f2b(lo.x); cvt.s[1] = f2b(lo.y); cvt.s[2] = f2b(lo.z); cvt.s[3] = f2b(lo.w);
    cvt.s[4] = f2b(hi.x); cvt.s[5] = f2b(hi.y); cvt.s[6] = f2b(hi.z); cvt.s[7] = f2b(hi.w);
    bfrag[kk] = cvt.v;
  }

  // A staging, phase 1: batch-issue 8 float4 loads (32 VGPRs in flight)
  const float4* f4 = reinterpret_cast<const float4*>(feat);
  float4 v[8];
#pragma unroll
  for (int i = 0; i < 8; ++i) {
    int c  = tid + 512 * i;
    int r  = c >> 6, c4 = c & 63;
    int row = m0 + r;
    v[i] = make_float4(0.f, 0.f, 0.f, 0.f);
    if (row < M) v[i] = f4[(size_t)row * 64 + c4];
  }
  // phase 2: convert + LDS write
#pragma unroll
  for (int i = 0; i < 8; ++i) {
    int c = tid + 512 * i;
    int r = c >> 6, c4 = c & 63;
    ushort4 bq;
    bq.x = f2b(v[i].x); bq.y = f2b(v[i].y); bq.z = f2b(v[i].z); bq.w = f2b(v[i].w);
    *reinterpret_cast<ushort4*>(&As[r][c4 * 4]) = bq;
  }
  __syncthreads();

  f32x4 acc[BM / 16] = {};
  const int arow = lane & 15;
  const int q    = lane >> 4;
#pragma unroll
  for (int mt = 0; mt < BM / 16; ++mt) {
#pragma unroll
    for (int kk = 0; kk < 8; ++kk) {
      bf16x8 a = *reinterpret_cast<const bf16x8*>(&As[mt * 16 + arow][kk * 32 + kof]);
      acc[mt] = __builtin_amdgcn_mfma_f32_16x16x32_bf16(a, bfrag[kk], acc[mt], 0, 0, 0);
    }
  }

  // D layout: col = lane&15, row = (lane>>4)*4 + reg   [m89-verified]
#pragma unroll
  for (int mt = 0; mt < BM / 16; ++mt) {
    int rbase = m0 + mt * 16 + q * 4;
#pragma unroll
    for (int r = 0; r < 4; ++r) {
      int row = rbase + r;
      if (row < M) z[(size_t)row * EMB + col] = f2b(acc[mt][r]);
    }
  }
}

// ---- per-edge aggregation + classifier ----------------------------------
// one block (128 threads = 2 waves) per edge; wave w = endpoint p.
// Lane half h=l>>5 covers row-parity h of each pair; lane q=l&31 owns dims
// 4q..4q+3 (uint2 per row). Pairs are k-aligned (rows {2m,2m+1} share k).
// R10: 2 k-groups; per group batch-issue 25 pair-loads into registers
// (compile-time indexing -> VGPRs, not scratch), then unpack/accumulate.

__global__ __launch_bounds__(128) void aggregate(
    const int* __restrict__ edges, const int* __restrict__ nidx,
    const unsigned short* __restrict__ z, const float* __restrict__ M2,
    float* __restrict__ out, int E) {
  __shared__ int   s_idx2[2][KNB];
  __shared__ int   s_idx1[2][KNB * KNB];
  __shared__ float s_pm[2][EMB];

  const int e = blockIdx.x;
  const int t = threadIdx.x;
  const int w = t >> 6;
  const int l = t & 63;
  const int h = l >> 5;
  const int q = l & 31;

  if (t < 2 * KNB) {
    int p = t / KNB, k = t % KNB;
    int v = edges[e * 2 + p];
    s_idx2[p][k] = nidx[(size_t)v * KNB + k];
  }
  __syncthreads();
  for (int i = t; i < 2 * KNB * KNB; i += 128) {
    int p = i / 100, r = i % 100;
    s_idx1[p][r] = nidx[(size_t)s_idx2[p][r / KNB] * KNB + (r % KNB)];
  }
  __syncthreads();

  float pooled[4] = {0.f, 0.f, 0.f, 0.f};
#pragma unroll
  for (int kg = 0; kg < 2; ++kg) {
    // batch-issue 25 pair-loads (rows 2*gp+h for gp = kg*25+m)
    uint2 u[25];
#pragma unroll
    for (int m = 0; m < 25; ++m) {
      int idx = s_idx1[w][(kg * 25 + m) * 2 + h];
      u[m] = *reinterpret_cast<const uint2*>(&z[(size_t)idx * EMB + q * 4]);
    }
    // unpack + accumulate: group holds k = kg*5 .. kg*5+4, 5 pairs each
#pragma unroll
    for (int kk = 0; kk < 5; ++kk) {
      float a[4] = {0.f, 0.f, 0.f, 0.f};
#pragma unroll
      for (int jm = 0; jm < 5; ++jm) {
        uint2 vv = u[kk * 5 + jm];
        a[0] += b2f(vv.x & 0xffffu); a[1] += b2f(vv.x >> 16);
        a[2] += b2f(vv.y & 0xffffu); a[3] += b2f(vv.y >> 16);
      }
#pragma unroll
      for (int c = 0; c < 4; ++c) {
        float s = a[c] + __shfl_xor(a[c], 32);   // combine row parities: 10-row sum
        pooled[c] += fmaxf(s * 0.1f, 0.f);       // relu(mean_j)
      }
    }
  }
  if (h == 0) {
#pragma unroll
    for (int c = 0; c < 4; ++c) s_pm[w][q * 4 + c] = pooled[c] * 0.1f;  // mean_k
  }
  __syncthreads();

  if (w == 0) {
    int d0 = 2 * l, d1 = 2 * l + 1;
    float p0 = 0.5f * (s_pm[0][d0] + s_pm[1][d0]);
    float p1 = 0.5f * (s_pm[0][d1] + s_pm[1][d1]);
    float s0 = p0 * M2[d0]       + p1 * M2[d1];
    float s1 = p0 * M2[EMB + d0] + p1 * M2[EMB + d1];
#pragma unroll
    for (int off = 32; off > 0; off >>= 1) {
      s0 += __shfl_down(s0, off);
      s1 += __shfl_down(s1, off);
    }
    if (l == 0) { out[e * 2 + 0] = s0; out[e * 2 + 1] = s1; }
  }
}

// ---- launcher -----------------------------------------------------------

extern "C" void kernel_launch(void* const* d_in, const int* in_sizes, int n_in,
                              void* d_out, int out_size, void* d_ws, size_t ws_size,
                              hipStream_t stream) {
  const int*   edges = (const int*)d_in[0];
  const int*   nidx  = (const int*)d_in[1];
  const float* feat  = (const float*)d_in[2];
  const float* W1    = (const float*)d_in[3];
  const float* W2    = (const float*)d_in[4];
  const float* Wc    = (const float*)d_in[5];
  float* out = (float*)d_out;

  const int N = in_sizes[2] / FEAT;   // 100000
  const int E = in_sizes[0] / 2;      // 4096

  char* ws = (char*)d_ws;
  unsigned short* z = (unsigned short*)ws;                         // N*128 bf16
  float* M2 = (float*)(ws + (size_t)N * EMB * sizeof(unsigned short));

  const int mtiles = (N + BM - 1) / BM;   // 1563
  gemm_z   <<<mtiles + 1, 512, 0, stream>>>(feat, W1, W2, Wc, z, M2, N);
  aggregate<<<E, 128, 0, stream>>>(edges, nidx, z, M2, out, E);
}